// Round 8
// baseline (439.489 us; speedup 1.0000x reference)
//
#include <hip/hip_runtime.h>

typedef unsigned short u16;
typedef short bf16x8 __attribute__((ext_vector_type(8)));
typedef float f32x4 __attribute__((ext_vector_type(4)));

#define BSZ 4
#define DD 1024
#define LLL 1024

__device__ __forceinline__ float bf2f(u16 u) {
    union { unsigned int i; float f; } w;
    w.i = ((unsigned int)u) << 16;
    return w.f;
}
__device__ __forceinline__ u16 f2bf(float f) {
    union { float fl; unsigned int i; } w;
    w.fl = f;
    w.i += 0x7fffu + ((w.i >> 16) & 1u);   // RNE
    return (u16)(w.i >> 16);
}

// async global->LDS, 16B per lane; LDS dst must be wave-uniform base + lane*16
__device__ __forceinline__ void load_lds16(const u16* g, u16* l) {
    __builtin_amdgcn_global_load_lds(
        (const __attribute__((address_space(1))) unsigned int*)g,
        (__attribute__((address_space(3))) unsigned int*)l, 16, 0, 0);
}

// ---- fused fp32->bf16 converts for x (4096 blk), Wi (2048), Wo (1024)
__global__ void cvt_all(const float* __restrict__ x, const float* __restrict__ Wi,
                        const float* __restrict__ Wo, u16* __restrict__ xb,
                        u16* __restrict__ wib, u16* __restrict__ wob) {
    int b = blockIdx.x;
    const float* in; u16* out;
    if (b < 4096)      { in = x;  out = xb; }
    else if (b < 6144) { in = Wi; out = wib; b -= 4096; }
    else               { in = Wo; out = wob; b -= 6144; }
    const size_t i = ((size_t)b * 256 + threadIdx.x) * 4;
    const float4 v = *(const float4*)(in + i);
    ushort4 o;
    o.x = f2bf(v.x); o.y = f2bf(v.y); o.z = f2bf(v.z); o.w = f2bf(v.w);
    *(ushort4*)(out + i) = o;
}

// ---- batched transpose+convert: in[z][R][C] f32 -> out[z][C][R] bf16
__global__ void transpose_cvt(const float* __restrict__ in, u16* __restrict__ out,
                              int R, int C) {
    __shared__ float tile[32][33];
    const size_t base = (size_t)blockIdx.z * R * C;
    const int c0 = blockIdx.x << 5, r0 = blockIdx.y << 5;
    const int tx = threadIdx.x & 31, ty = threadIdx.x >> 5;   // 256 thr = 32x8
    #pragma unroll
    for (int i = 0; i < 32; i += 8)
        tile[ty + i][tx] = in[base + (size_t)(r0 + ty + i) * C + c0 + tx];
    __syncthreads();
    #pragma unroll
    for (int i = 0; i < 32; i += 8)
        out[base + (size_t)(c0 + ty + i) * R + r0 + tx] = f2bf(tile[tx][ty + i]);
}

// ---- build vt[j][d][m], d padded to 80: d=64 ones-column (rowsum), 65..79 zero
__global__ void build_vt(const u16* __restrict__ proj, u16* __restrict__ vt) {
    __shared__ u16 tile[64][66];
    const int t = threadIdx.x;
    const int m0 = blockIdx.x << 6;
    const int jj = blockIdx.y;
    const int b = jj >> 4, k = jj & 15;
    const int tx = t & 63, ty = t >> 6;
    #pragma unroll
    for (int mi = ty; mi < 64; mi += 4)
        tile[mi][tx] = proj[(size_t)((m0 + mi) * BSZ + b) * 2048 + 1024 + k * 64 + tx];
    __syncthreads();
    #pragma unroll
    for (int di = ty; di < 64; di += 4)
        vt[((size_t)jj * 80 + di) * 1024 + m0 + tx] = tile[tx][di];
    #pragma unroll
    for (int di = 64 + ty; di < 80; di += 4)
        vt[((size_t)jj * 80 + di) * 1024 + m0 + tx] = (di == 64) ? 0x3F80 : 0;
}

// ---- generic batched bf16 NT-GEMM (round-6-proven): 128x128 tile, BK=64,
// XOR chunk swizzle, global_load_lds width=16.
template<int OUT_F32, int RELU>
__global__ __launch_bounds__(256, 2) void gemm_bf16_nt(
    const u16* __restrict__ A, int lda, long long sA,
    const u16* __restrict__ B, int ldb, long long sB,
    const float* __restrict__ bias, int sBias,
    void* __restrict__ C, int ldc, long long sC,
    int K)
{
    __shared__ u16 As[128 * 64];
    __shared__ u16 Bs[128 * 64];
    const int t = threadIdx.x;
    const int z = blockIdx.z;
    const u16* Ab = A + (size_t)z * sA + (size_t)blockIdx.x * 128 * lda;
    const u16* Bb = B + (size_t)z * sB + (size_t)blockIdx.y * 128 * ldb;
    const int wave = t >> 6, lane = t & 63;
    const int wrow = (wave >> 1) << 6;
    const int wcol = (wave & 1) << 6;
    const int lr = lane & 15, lq = lane >> 4;
    const int srow = t >> 3;
    const int gchunk = (t & 7) ^ (srow & 7);
    const u16* ApG = Ab + (size_t)srow * lda + gchunk * 8;
    const u16* BpG = Bb + (size_t)srow * ldb + gchunk * 8;
    u16* AsD = &As[t * 8];
    u16* BsD = &Bs[t * 8];
    const int o0 = ((lq    ) ^ (lr & 7)) * 8;
    const int o1 = ((lq + 4) ^ (lr & 7)) * 8;

    f32x4 acc[4][4];
    #pragma unroll
    for (int i = 0; i < 4; i++)
        #pragma unroll
        for (int j = 0; j < 4; j++)
            acc[i][j] = (f32x4){0.f, 0.f, 0.f, 0.f};

    for (int k0 = 0; k0 < K; k0 += 64) {
        __syncthreads();
        #pragma unroll
        for (int j = 0; j < 4; j++) {
            load_lds16(ApG + (size_t)j * 32 * lda + k0, AsD + j * 2048);
            load_lds16(BpG + (size_t)j * 32 * ldb + k0, BsD + j * 2048);
        }
        __syncthreads();
        #pragma unroll
        for (int s = 0; s < 2; s++) {
            const int oo = s ? o1 : o0;
            bf16x8 af[4], bfv[4];
            #pragma unroll
            for (int i = 0; i < 4; i++)
                af[i] = *(const bf16x8*)&As[(wrow + i * 16 + lr) * 64 + oo];
            #pragma unroll
            for (int j = 0; j < 4; j++)
                bfv[j] = *(const bf16x8*)&Bs[(wcol + j * 16 + lr) * 64 + oo];
            #pragma unroll
            for (int i = 0; i < 4; i++)
                #pragma unroll
                for (int j = 0; j < 4; j++)
                    acc[i][j] = __builtin_amdgcn_mfma_f32_16x16x32_bf16(
                        af[i], bfv[j], acc[i][j], 0, 0, 0);
        }
    }

    const float* biasb = bias + (size_t)z * sBias;
    const size_t row0 = (size_t)blockIdx.x * 128 + wrow + lq * 4;
    const int col0 = blockIdx.y * 128 + wcol + lr;
    #pragma unroll
    for (int j = 0; j < 4; j++) {
        const int col = col0 + j * 16;
        const float bb = biasb[col];
        #pragma unroll
        for (int i = 0; i < 4; i++) {
            #pragma unroll
            for (int r = 0; r < 4; r++) {
                const size_t row = row0 + i * 16 + r;
                float v = acc[i][j][r] + bb;
                if (RELU) v = fmaxf(v, 0.f);
                const size_t idx = row * (size_t)ldc + col;
                if (OUT_F32) ((float*)C)[(size_t)z * sC + idx] = v;
                else         ((u16*)C)[(size_t)z * sC + idx] = f2bf(v);
            }
        }
    }
}

// ---- fused logits+softmax+PV, bq-merged.
// Block = (kq, pair). Parts: strip s = pair, then 63-pair (16 l-rows x 4 bq =
// 64 A-rows). nt(s) = s/8+1 causal m-tiles; pairing gives exactly 9 units.
// A-tile row rt = bq*16 + r  (r = rt&15, bq = rt>>4) -> hid row (l0+r)*4+bq.
// Causal mask via compare (mask = 0/-1e9 exactly); rowsum via vt ones-column.
__global__ __launch_bounds__(256, 2) void fused_attn(
    const u16* __restrict__ hid,    // (16, 4096, 1024) bf16
    const u16* __restrict__ w2t,    // (16, 1024, 1024) bf16 [k][m][h]
    const float* __restrict__ b2,   // (16, 1024) fp32
    const u16* __restrict__ vt,     // (64, 80, 1024) bf16
    u16* __restrict__ attn)         // (4096, 1024) bf16
{
    __shared__ u16 As[64 * 64];     // hid tile: 64 A-rows x 64 k
    __shared__ u16 Bs[128 * 64];    // w2t tile: 128 m x 64 k
    __shared__ u16 Ps[64 * 136];    // probs: 64 rows x 128 m (+8 pad)
    const int t = threadIdx.x;
    const int kq = blockIdx.x;      // 0..15 (x-dim -> XCD affinity)
    const int pair = blockIdx.y;    // 0..31
    const int wave = t >> 6, lane = t & 63;
    const int lr = lane & 15, lq = lane >> 4;
    const int wi = wave >> 1, wj = wave & 1;
    const int srow = t >> 3;                    // 0..31
    const int gch = (t & 7) ^ (srow & 7);       // XOR chunk swizzle
    const int o0 = ((lq    ) ^ (lr & 7)) * 8;
    const int o1 = ((lq + 4) ^ (lr & 7)) * 8;
    const int bv = kq >> 2;
    const int kvb = 4 * (kq & 3);               // kv = kvb + bq
    const u16* hb = hid + (size_t)kq * 4194304;
    const u16* wb = w2t + (size_t)kq * 1048576 + (size_t)srow * 1024 + gch * 8;
    const float* b2b = b2 + kq * 1024;

    for (int part = 0; part < 2; part++) {
        const int s = part ? (63 - pair) : pair;
        const int l0 = s << 4;
        const int nt = (s >> 3) + 1;
        // A staging srcs: tile rows srow (bq=srow>>4) and srow+32 (bq+2)
        const u16* ApG0 = hb + (size_t)((l0 + (srow & 15)) * 4 + (srow >> 4)) * 1024 + gch * 8;
        const u16* ApG1 = ApG0 + (size_t)2 * 1024;
        f32x4 o[2][5];
        #pragma unroll
        for (int i = 0; i < 2; i++)
            #pragma unroll
            for (int j = 0; j < 5; j++)
                o[i][j] = (f32x4){0.f, 0.f, 0.f, 0.f};

        for (int mt = 0; mt < nt; mt++) {
            // ---- logits tile 64(rows) x 128(m), K=1024
            f32x4 acc[2][4];
            #pragma unroll
            for (int i = 0; i < 2; i++)
                #pragma unroll
                for (int j = 0; j < 4; j++)
                    acc[i][j] = (f32x4){0.f, 0.f, 0.f, 0.f};
            for (int k0 = 0; k0 < 1024; k0 += 64) {
                __syncthreads();
                load_lds16(ApG0 + k0, &As[t * 8]);
                load_lds16(ApG1 + k0, &As[t * 8 + 2048]);
                #pragma unroll
                for (int j2 = 0; j2 < 4; j2++)
                    load_lds16(wb + (size_t)(mt * 128 + j2 * 32) * 1024 + k0,
                               &Bs[j2 * 2048 + t * 8]);
                __syncthreads();
                #pragma unroll
                for (int s2 = 0; s2 < 2; s2++) {
                    const int oo = s2 ? o1 : o0;
                    bf16x8 af[2], bfv[4];
                    #pragma unroll
                    for (int i = 0; i < 2; i++)
                        af[i] = *(const bf16x8*)&As[(wi * 32 + i * 16 + lr) * 64 + oo];
                    #pragma unroll
                    for (int j = 0; j < 4; j++)
                        bfv[j] = *(const bf16x8*)&Bs[(wj * 64 + j * 16 + lr) * 64 + oo];
                    #pragma unroll
                    for (int i = 0; i < 2; i++)
                        #pragma unroll
                        for (int j = 0; j < 4; j++)
                            acc[i][j] = __builtin_amdgcn_mfma_f32_16x16x32_bf16(
                                af[i], bfv[j], acc[i][j], 0, 0, 0);
                }
            }
            // ---- +b2, causal compare, exp -> Ps (bf16)
            __syncthreads();   // prior PV reads of Ps complete (also k-loop bars)
            const int l = l0 + lq * 4;         // + rr below; row l for this lane
            float b2v[4];
            #pragma unroll
            for (int j = 0; j < 4; j++)
                b2v[j] = b2b[mt * 128 + wj * 64 + j * 16 + lr];
            #pragma unroll
            for (int i = 0; i < 2; i++) {
                #pragma unroll
                for (int j = 0; j < 4; j++) {
                    const int cp = wj * 64 + j * 16 + lr;
                    const int m = mt * 128 + cp;
                    #pragma unroll
                    for (int rr = 0; rr < 4; rr++) {
                        const int rt = wi * 32 + i * 16 + lq * 4 + rr;
                        const float e = __expf(acc[i][j][rr] + b2v[j]);
                        Ps[rt * 136 + cp] = (m <= l + rr) ? f2bf(e) : (u16)0;
                    }
                }
            }
            __syncthreads();
            // ---- O += P @ V^T: wave wi owns row-tiles {2wi, 2wi+1} (bq-uniform)
            #pragma unroll
            for (int i = 0; i < 2; i++) {
                const int bq = 2 * wi + i;
                const u16* vbb = vt + (size_t)(kq * 4 + bq) * 80 * 1024
                               + (size_t)mt * 128 + lq * 8;
                #pragma unroll
                for (int kc = 0; kc < 4; kc++) {
                    const bf16x8 a = *(const bf16x8*)
                        &Ps[(wi * 32 + i * 16 + lr) * 136 + kc * 32 + lq * 8];
                    #pragma unroll
                    for (int j = 0; j < 5; j++) {
                        const bf16x8 b = *(const bf16x8*)
                            (vbb + (size_t)(j * 16 + lr) * 1024 + kc * 32);
                        o[i][j] = __builtin_amdgcn_mfma_f32_16x16x32_bf16(
                            a, b, o[i][j], 0, 0, 0);
                    }
                }
            }
        }
        // ---- normalize by rowsum (ones-column d=64 -> o[i][4], lanes lr==0)
        #pragma unroll
        for (int i = 0; i < 2; i++) {
            const int bq = 2 * wi + i;
            float sden[4];
            #pragma unroll
            for (int rr = 0; rr < 4; rr++)
                sden[rr] = __shfl(o[i][4][rr], lq << 4);
            #pragma unroll
            for (int j = 0; j < 4; j++) {
                #pragma unroll
                for (int rr = 0; rr < 4; rr++) {
                    const int l = l0 + lq * 4 + rr;
                    attn[(size_t)(l * BSZ + bv) * 1024 + (kvb + bq) * 64 + j * 16 + lr]
                        = f2bf(o[i][j][rr] / sden[rr]);
                }
            }
        }
    }
}

extern "C" void kernel_launch(void* const* d_in, const int* in_sizes, int n_in,
                              void* d_out, int out_size, void* d_ws, size_t ws_size,
                              hipStream_t stream)
{
    (void)in_sizes; (void)n_in; (void)out_size; (void)ws_size;
    const float* x  = (const float*)d_in[0];
    const float* Wi = (const float*)d_in[2];
    const float* bi = (const float*)d_in[3];
    const float* w1 = (const float*)d_in[4];
    const float* b1 = (const float*)d_in[5];
    const float* w2 = (const float*)d_in[6];
    const float* b2 = (const float*)d_in[7];
    const float* Wo = (const float*)d_in[8];
    const float* bo = (const float*)d_in[9];

    // ws layout (bf16 elems): 110.06M elems = 220 MB <= 256 MiB
    u16* x_b    = (u16*)d_ws;                  // 4096x1024       = 4M
    u16* Wi_b   = x_b    + (size_t)4194304;    // 2048x1024       = 2M
    u16* w1t    = Wi_b   + (size_t)2097152;    // 16 x 1024x64    = 1M
    u16* w2t    = w1t    + (size_t)1048576;    // 16 x 1024x1024  = 16M
    u16* Wo_b   = w2t    + (size_t)16777216;   // 1024x1024       = 1M
    u16* proj_b = Wo_b   + (size_t)1048576;    // 4096x2048       = 8M
    u16* attn_b = proj_b + (size_t)8388608;    // 4096x1024       = 4M
    u16* vt     = attn_b + (size_t)4194304;    // 64 x 80 x 1024  = 5M
    u16* hid_a  = vt     + (size_t)5242880;    // 16 x 4096x1024  = 64M

    // ---- prep
    cvt_all<<<7168, 256, 0, stream>>>(x, Wi, Wo, x_b, Wi_b, Wo_b);
    transpose_cvt<<<dim3(32,  2, 16), 256, 0, stream>>>(w1, w1t, 64,   1024);
    transpose_cvt<<<dim3(32, 32, 16), 256, 0, stream>>>(w2, w2t, 1024, 1024);

    // ---- proj = x @ Wi.T + bi  -> bf16 (4096 x 2048)
    gemm_bf16_nt<0, 0><<<dim3(32, 16, 1), 256, 0, stream>>>(
        x_b, 1024, 0, Wi_b, 1024, 0, bi, 0, (void*)proj_b, 2048, 0, 1024);

    // ---- vt[j][d(80)][m] from proj's v-half (with ones-column at d=64)
    build_vt<<<dim3(16, 64), 256, 0, stream>>>(proj_b, vt);

    // ---- hid = relu(q @ w1t.T + b1) for all 16 heads (z=16)
    gemm_bf16_nt<0, 1><<<dim3(32, 8, 16), 256, 0, stream>>>(
        proj_b, 2048, 64,
        w1t, 64, 65536,
        b1, 1024,
        (void*)hid_a, 1024, 4194304, 64);

    // ---- fused logits + softmax + PV (bq-merged, causal-skip, paired strips)
    fused_attn<<<dim3(16, 32), 256, 0, stream>>>(hid_a, w2t, b2, vt, attn_b);

    // ---- out = attn @ Wo.T + bo -> fp32 (4096 x 1024)
    gemm_bf16_nt<1, 0><<<dim3(32, 8, 1), 256, 0, stream>>>(
        attn_b, 1024, 0, Wo_b, 1024, 0, bo, 0, d_out, 1024, 0, 1024);
}

// Round 9
// 397.624 us; speedup vs baseline: 1.1053x; 1.1053x over previous
//
#include <hip/hip_runtime.h>

typedef unsigned short u16;
typedef short bf16x8 __attribute__((ext_vector_type(8)));
typedef float f32x4 __attribute__((ext_vector_type(4)));

#define BSZ 4
#define DD 1024
#define LLL 1024

__device__ __forceinline__ float bf2f(u16 u) {
    union { unsigned int i; float f; } w;
    w.i = ((unsigned int)u) << 16;
    return w.f;
}
__device__ __forceinline__ u16 f2bf(float f) {
    union { float fl; unsigned int i; } w;
    w.fl = f;
    w.i += 0x7fffu + ((w.i >> 16) & 1u);   // RNE
    return (u16)(w.i >> 16);
}

// async global->LDS, 16B per lane; LDS dst must be wave-uniform base + lane*16
__device__ __forceinline__ void load_lds16(const u16* g, u16* l) {
    __builtin_amdgcn_global_load_lds(
        (const __attribute__((address_space(1))) unsigned int*)g,
        (__attribute__((address_space(3))) unsigned int*)l, 16, 0, 0);
}

// ---- fused fp32->bf16 converts for x (4096 blk), Wi (2048), Wo (1024)
__global__ void cvt_all(const float* __restrict__ x, const float* __restrict__ Wi,
                        const float* __restrict__ Wo, u16* __restrict__ xb,
                        u16* __restrict__ wib, u16* __restrict__ wob) {
    int b = blockIdx.x;
    const float* in; u16* out;
    if (b < 4096)      { in = x;  out = xb; }
    else if (b < 6144) { in = Wi; out = wib; b -= 4096; }
    else               { in = Wo; out = wob; b -= 6144; }
    const size_t i = ((size_t)b * 256 + threadIdx.x) * 4;
    const float4 v = *(const float4*)(in + i);
    ushort4 o;
    o.x = f2bf(v.x); o.y = f2bf(v.y); o.z = f2bf(v.z); o.w = f2bf(v.w);
    *(ushort4*)(out + i) = o;
}

// ---- batched transpose+convert: in[z][R][C] f32 -> out[z][C][R] bf16
__global__ void transpose_cvt(const float* __restrict__ in, u16* __restrict__ out,
                              int R, int C) {
    __shared__ float tile[32][33];
    const size_t base = (size_t)blockIdx.z * R * C;
    const int c0 = blockIdx.x << 5, r0 = blockIdx.y << 5;
    const int tx = threadIdx.x & 31, ty = threadIdx.x >> 5;   // 256 thr = 32x8
    #pragma unroll
    for (int i = 0; i < 32; i += 8)
        tile[ty + i][tx] = in[base + (size_t)(r0 + ty + i) * C + c0 + tx];
    __syncthreads();
    #pragma unroll
    for (int i = 0; i < 32; i += 8)
        out[base + (size_t)(c0 + ty + i) * R + r0 + tx] = f2bf(tile[tx][ty + i]);
}

// ---- build vt[j][d][m], d padded to 80: d=64 ones-column (rowsum), 65..79 zero
__global__ void build_vt(const u16* __restrict__ proj, u16* __restrict__ vt) {
    __shared__ u16 tile[64][66];
    const int t = threadIdx.x;
    const int m0 = blockIdx.x << 6;
    const int jj = blockIdx.y;
    const int b = jj >> 4, k = jj & 15;
    const int tx = t & 63, ty = t >> 6;
    #pragma unroll
    for (int mi = ty; mi < 64; mi += 4)
        tile[mi][tx] = proj[(size_t)((m0 + mi) * BSZ + b) * 2048 + 1024 + k * 64 + tx];
    __syncthreads();
    #pragma unroll
    for (int di = ty; di < 64; di += 4)
        vt[((size_t)jj * 80 + di) * 1024 + m0 + tx] = tile[tx][di];
    #pragma unroll
    for (int di = 64 + ty; di < 80; di += 4)
        vt[((size_t)jj * 80 + di) * 1024 + m0 + tx] = (di == 64) ? 0x3F80 : 0;
}

// ---- generic batched bf16 NT-GEMM (round-6-proven): 128x128 tile, BK=64,
// XOR chunk swizzle, global_load_lds width=16.
template<int OUT_F32, int RELU>
__global__ __launch_bounds__(256, 2) void gemm_bf16_nt(
    const u16* __restrict__ A, int lda, long long sA,
    const u16* __restrict__ B, int ldb, long long sB,
    const float* __restrict__ bias, int sBias,
    void* __restrict__ C, int ldc, long long sC,
    int K)
{
    __shared__ u16 As[128 * 64];
    __shared__ u16 Bs[128 * 64];
    const int t = threadIdx.x;
    const int z = blockIdx.z;
    const u16* Ab = A + (size_t)z * sA + (size_t)blockIdx.x * 128 * lda;
    const u16* Bb = B + (size_t)z * sB + (size_t)blockIdx.y * 128 * ldb;
    const int wave = t >> 6, lane = t & 63;
    const int wrow = (wave >> 1) << 6;
    const int wcol = (wave & 1) << 6;
    const int lr = lane & 15, lq = lane >> 4;
    const int srow = t >> 3;
    const int gchunk = (t & 7) ^ (srow & 7);
    const u16* ApG = Ab + (size_t)srow * lda + gchunk * 8;
    const u16* BpG = Bb + (size_t)srow * ldb + gchunk * 8;
    u16* AsD = &As[t * 8];
    u16* BsD = &Bs[t * 8];
    const int o0 = ((lq    ) ^ (lr & 7)) * 8;
    const int o1 = ((lq + 4) ^ (lr & 7)) * 8;

    f32x4 acc[4][4];
    #pragma unroll
    for (int i = 0; i < 4; i++)
        #pragma unroll
        for (int j = 0; j < 4; j++)
            acc[i][j] = (f32x4){0.f, 0.f, 0.f, 0.f};

    for (int k0 = 0; k0 < K; k0 += 64) {
        __syncthreads();
        #pragma unroll
        for (int j = 0; j < 4; j++) {
            load_lds16(ApG + (size_t)j * 32 * lda + k0, AsD + j * 2048);
            load_lds16(BpG + (size_t)j * 32 * ldb + k0, BsD + j * 2048);
        }
        __syncthreads();
        #pragma unroll
        for (int s = 0; s < 2; s++) {
            const int oo = s ? o1 : o0;
            bf16x8 af[4], bfv[4];
            #pragma unroll
            for (int i = 0; i < 4; i++)
                af[i] = *(const bf16x8*)&As[(wrow + i * 16 + lr) * 64 + oo];
            #pragma unroll
            for (int j = 0; j < 4; j++)
                bfv[j] = *(const bf16x8*)&Bs[(wcol + j * 16 + lr) * 64 + oo];
            #pragma unroll
            for (int i = 0; i < 4; i++)
                #pragma unroll
                for (int j = 0; j < 4; j++)
                    acc[i][j] = __builtin_amdgcn_mfma_f32_16x16x32_bf16(
                        af[i], bfv[j], acc[i][j], 0, 0, 0);
        }
    }

    const float* biasb = bias + (size_t)z * sBias;
    const size_t row0 = (size_t)blockIdx.x * 128 + wrow + lq * 4;
    const int col0 = blockIdx.y * 128 + wcol + lr;
    #pragma unroll
    for (int j = 0; j < 4; j++) {
        const int col = col0 + j * 16;
        const float bb = biasb[col];
        #pragma unroll
        for (int i = 0; i < 4; i++) {
            #pragma unroll
            for (int r = 0; r < 4; r++) {
                const size_t row = row0 + i * 16 + r;
                float v = acc[i][j][r] + bb;
                if (RELU) v = fmaxf(v, 0.f);
                const size_t idx = row * (size_t)ldc + col;
                if (OUT_F32) ((float*)C)[(size_t)z * sC + idx] = v;
                else         ((u16*)C)[(size_t)z * sC + idx] = f2bf(v);
            }
        }
    }
}

// ---- fused logits+softmax+PV, bq-merged, m-tile = 256.
// Block = (kq, pair). Strips s = pair and 63-pair; 16 l-rows x 4 bq = 64 A-rows.
// nt(s) = s/16+1 causal m-tiles of 256; pairing gives exactly 5 per block.
// A-tile row rt = bq*16 + r (r = rt&15) -> hid row (l0+r)*4+bq.
// PV: wave w owns bq = w (no duplication). Rowsum via vt ones-column (d=64).
__global__ __launch_bounds__(256, 2) void fused_attn(
    const u16* __restrict__ hid,    // (16, 4096, 1024) bf16
    const u16* __restrict__ w2t,    // (16, 1024, 1024) bf16 [k][m][h]
    const float* __restrict__ b2,   // (16, 1024) fp32
    const u16* __restrict__ vt,     // (64, 80, 1024) bf16
    u16* __restrict__ attn)         // (4096, 1024) bf16
{
    __shared__ u16 As[64 * 64];     // hid tile: 64 A-rows x 64 k     (8 KB)
    __shared__ u16 Bs[256 * 64];    // w2t tile: 256 m x 64 k         (32 KB)
    __shared__ u16 Ps[64 * 264];    // probs: 64 rows x 256 m (+8)    (33.8 KB)
    const int t = threadIdx.x;
    const int kq = blockIdx.x;      // 0..15 (x-dim -> XCD affinity)
    const int pair = blockIdx.y;    // 0..31
    const int wave = t >> 6, lane = t & 63;
    const int lr = lane & 15, lq = lane >> 4;
    const int wi = wave >> 1, wj = wave & 1;
    const int srow = t >> 3;                    // 0..31
    const int gch = (t & 7) ^ (srow & 7);       // XOR chunk swizzle
    const int o0 = ((lq    ) ^ (lr & 7)) * 8;
    const int o1 = ((lq + 4) ^ (lr & 7)) * 8;
    const int bv = kq >> 2;
    const int kvb = 4 * (kq & 3);               // kv = kvb + bq
    const u16* hb = hid + (size_t)kq * 4194304;
    const u16* wb = w2t + (size_t)kq * 1048576 + (size_t)srow * 1024 + gch * 8;
    const float* b2b = b2 + kq * 1024;

    for (int part = 0; part < 2; part++) {
        const int s = part ? (63 - pair) : pair;
        const int l0 = s << 4;
        const int nt = (s >> 4) + 1;
        // A staging: LDS rows srow (bq=srow>>4) and srow+32 (bq+2)
        const u16* ApG0 = hb + (size_t)((l0 + (srow & 15)) * 4 + (srow >> 4)) * 1024 + gch * 8;
        const u16* ApG1 = ApG0 + (size_t)2 * 1024;
        f32x4 o[5];
        #pragma unroll
        for (int j = 0; j < 5; j++) o[j] = (f32x4){0.f, 0.f, 0.f, 0.f};

        for (int mt = 0; mt < nt; mt++) {
            // ---- logits tile 64(rows) x 256(m), K=1024
            f32x4 acc[2][8];
            #pragma unroll
            for (int i = 0; i < 2; i++)
                #pragma unroll
                for (int j = 0; j < 8; j++)
                    acc[i][j] = (f32x4){0.f, 0.f, 0.f, 0.f};
            for (int k0 = 0; k0 < 1024; k0 += 64) {
                __syncthreads();
                load_lds16(ApG0 + k0, &As[t * 8]);
                load_lds16(ApG1 + k0, &As[t * 8 + 2048]);
                #pragma unroll
                for (int j2 = 0; j2 < 8; j2++)
                    load_lds16(wb + (size_t)(mt * 256 + j2 * 32) * 1024 + k0,
                               &Bs[j2 * 2048 + t * 8]);
                __syncthreads();
                #pragma unroll
                for (int s2 = 0; s2 < 2; s2++) {
                    const int oo = s2 ? o1 : o0;
                    bf16x8 af[2], bfv[8];
                    #pragma unroll
                    for (int i = 0; i < 2; i++)
                        af[i] = *(const bf16x8*)&As[(wi * 32 + i * 16 + lr) * 64 + oo];
                    #pragma unroll
                    for (int j = 0; j < 8; j++)
                        bfv[j] = *(const bf16x8*)
                            &Bs[(wj * 128 + j * 16 + lr) * 64 + oo];
                    #pragma unroll
                    for (int i = 0; i < 2; i++)
                        #pragma unroll
                        for (int j = 0; j < 8; j++)
                            acc[i][j] = __builtin_amdgcn_mfma_f32_16x16x32_bf16(
                                af[i], bfv[j], acc[i][j], 0, 0, 0);
                }
            }
            // ---- +b2, causal compare, exp -> Ps (bf16)
            __syncthreads();   // prior PV reads of Ps complete
            float b2v[8];
            #pragma unroll
            for (int j = 0; j < 8; j++)
                b2v[j] = b2b[mt * 256 + wj * 128 + j * 16 + lr];
            #pragma unroll
            for (int i = 0; i < 2; i++) {
                #pragma unroll
                for (int j = 0; j < 8; j++) {
                    const int cp = wj * 128 + j * 16 + lr;
                    const int m = mt * 256 + cp;
                    #pragma unroll
                    for (int rr = 0; rr < 4; rr++) {
                        const int rt = wi * 32 + i * 16 + lq * 4 + rr;
                        const int l = l0 + lq * 4 + rr;   // rt&15 == lq*4+rr
                        const float e = __expf(acc[i][j][rr] + b2v[j]);
                        Ps[rt * 264 + cp] = (m <= l) ? f2bf(e) : (u16)0;
                    }
                }
            }
            __syncthreads();
            // ---- O += P @ V^T: wave w owns bq = w (rows w*16..w*16+15)
            {
                const u16* vbb = vt + (size_t)(kq * 4 + wave) * 80 * 1024
                               + (size_t)mt * 256 + lq * 8;
                #pragma unroll
                for (int kc = 0; kc < 8; kc++) {
                    const bf16x8 a = *(const bf16x8*)
                        &Ps[(wave * 16 + lr) * 264 + kc * 32 + lq * 8];
                    #pragma unroll
                    for (int j = 0; j < 5; j++) {
                        const bf16x8 b = *(const bf16x8*)
                            (vbb + (size_t)(j * 16 + lr) * 1024 + kc * 32);
                        o[j] = __builtin_amdgcn_mfma_f32_16x16x32_bf16(
                            a, b, o[j], 0, 0, 0);
                    }
                }
            }
        }
        // ---- normalize by rowsum (ones-column d=64 -> o[4], lanes lr==0)
        {
            const int bq = wave;
            float sden[4];
            #pragma unroll
            for (int rr = 0; rr < 4; rr++)
                sden[rr] = __shfl(o[4][rr], lq << 4);
            #pragma unroll
            for (int j = 0; j < 4; j++) {
                #pragma unroll
                for (int rr = 0; rr < 4; rr++) {
                    const int l = l0 + lq * 4 + rr;
                    attn[(size_t)(l * BSZ + bv) * 1024 + (kvb + bq) * 64 + j * 16 + lr]
                        = f2bf(o[j][rr] / sden[rr]);
                }
            }
        }
    }
}

extern "C" void kernel_launch(void* const* d_in, const int* in_sizes, int n_in,
                              void* d_out, int out_size, void* d_ws, size_t ws_size,
                              hipStream_t stream)
{
    (void)in_sizes; (void)n_in; (void)out_size; (void)ws_size;
    const float* x  = (const float*)d_in[0];
    const float* Wi = (const float*)d_in[2];
    const float* bi = (const float*)d_in[3];
    const float* w1 = (const float*)d_in[4];
    const float* b1 = (const float*)d_in[5];
    const float* w2 = (const float*)d_in[6];
    const float* b2 = (const float*)d_in[7];
    const float* Wo = (const float*)d_in[8];
    const float* bo = (const float*)d_in[9];

    // ws layout (bf16 elems): 110.06M elems = 220 MB <= 256 MiB
    u16* x_b    = (u16*)d_ws;                  // 4096x1024       = 4M
    u16* Wi_b   = x_b    + (size_t)4194304;    // 2048x1024       = 2M
    u16* w1t    = Wi_b   + (size_t)2097152;    // 16 x 1024x64    = 1M
    u16* w2t    = w1t    + (size_t)1048576;    // 16 x 1024x1024  = 16M
    u16* Wo_b   = w2t    + (size_t)16777216;   // 1024x1024       = 1M
    u16* proj_b = Wo_b   + (size_t)1048576;    // 4096x2048       = 8M
    u16* attn_b = proj_b + (size_t)8388608;    // 4096x1024       = 4M
    u16* vt     = attn_b + (size_t)4194304;    // 64 x 80 x 1024  = 5M
    u16* hid_a  = vt     + (size_t)5242880;    // 16 x 4096x1024  = 64M

    // ---- prep
    cvt_all<<<7168, 256, 0, stream>>>(x, Wi, Wo, x_b, Wi_b, Wo_b);
    transpose_cvt<<<dim3(32,  2, 16), 256, 0, stream>>>(w1, w1t, 64,   1024);
    transpose_cvt<<<dim3(32, 32, 16), 256, 0, stream>>>(w2, w2t, 1024, 1024);

    // ---- proj = x @ Wi.T + bi  -> bf16 (4096 x 2048)
    gemm_bf16_nt<0, 0><<<dim3(32, 16, 1), 256, 0, stream>>>(
        x_b, 1024, 0, Wi_b, 1024, 0, bi, 0, (void*)proj_b, 2048, 0, 1024);

    // ---- vt[j][d(80)][m] from proj's v-half (with ones-column at d=64)
    build_vt<<<dim3(16, 64), 256, 0, stream>>>(proj_b, vt);

    // ---- hid = relu(q @ w1t.T + b1) for all 16 heads (z=16)
    gemm_bf16_nt<0, 1><<<dim3(32, 8, 16), 256, 0, stream>>>(
        proj_b, 2048, 64,
        w1t, 64, 65536,
        b1, 1024,
        (void*)hid_a, 1024, 4194304, 64);

    // ---- fused logits + softmax + PV (bq-merged, m256, causal-skip)
    fused_attn<<<dim3(16, 32), 256, 0, stream>>>(hid_a, w2t, b2, vt, attn_b);

    // ---- out = attn @ Wo.T + bo -> fp32 (4096 x 1024)
    gemm_bf16_nt<1, 0><<<dim3(32, 8, 1), 256, 0, stream>>>(
        attn_b, 1024, 0, Wo_b, 1024, 0, bo, 0, d_out, 1024, 0, 1024);
}